// Round 5
// baseline (159.786 us; speedup 1.0000x reference)
//
#include <hip/hip_runtime.h>

// HQQ 4-bit dequant + linear (Llama-7B up-proj, decode: 8 tokens)
// OUT=11008, IN=4096, GS=64, G=704512, OC=172 (=G/IN; OUT=64*OC)
// W_q: [32, G] int32 (one byte per word: hi nibble -> unpacked row rq,
//      lo nibble -> row rq+32 of the [64, G] tensor)
// Mapping: W_r[o, i] with r=o/172, oc=o%172, g=oc*4096+i.
// out[b, o] = sum_i x[b,i] * fma(nib, s[g], -z[g]*s[g]) + bias[o]
//
// R5 theory: R3/R4's stage->barrier->consume lockstep serializes memory and
// compute phases per block (vmcnt(0) drain at the barrier; zero loads in
// flight during compute). Fix: 1-wave blocks, NO barrier, NO LDS — x/s/z/Wq
// in a depth-1 register double-buffer so ~12 independent loads are in flight
// during every compute phase. x re-read from L2 (352 MB aggregate ~ 10 us,
// overlaps HBM). VGPR ~130 -> 3 waves/SIMD; 5504 waves = 5.4/SIMD demand.

#define OUT_ 11008
#define IN_ 4096
#define G_ 704512
#define OC_ 172
#define KS 2              // K-split factor
#define KC (IN_ / KS)     // 2048 K per wave
#define ITERS (KC / 256)  // 8

__global__ __launch_bounds__(64, 3)
void hqq_gemv(const int* __restrict__ Wq, const float* __restrict__ scale,
              const float* __restrict__ zero, const float* __restrict__ x,
              float* __restrict__ ws) {
    const int lane = threadIdx.x;             // 0..63 : K-slice
    const int oc   = blockIdx.y;              // 0..171
    const int ks   = blockIdx.z;              // 0..KS-1
    const int rq0  = blockIdx.x * 2;          // packed rows rq0, rq0+1

    const int kbase = ks * KC;
    const long gb = (long)oc * IN_ + kbase;
    const int* __restrict__ wqA = Wq + (long)rq0 * G_ + gb;
    const int* __restrict__ wqB = wqA + G_;
    const float* __restrict__ sp = scale + gb;
    const float* __restrict__ zp = zero + gb;
    const float* __restrict__ xp = x + kbase;

    // acc[0]=hi(rq0) acc[1]=lo(rq0) acc[2]=hi(rq0+1) acc[3]=lo(rq0+1)
    float acc[4][8];
#pragma unroll
    for (int r = 0; r < 4; ++r)
#pragma unroll
        for (int b = 0; b < 8; ++b) acc[r][b] = 0.f;

    const int i0 = lane * 4;

    // ---- prime the register pipeline (iter 0) ----
    int4  qa = *(const int4*)(wqA + i0);
    int4  qb = *(const int4*)(wqB + i0);
    float4 s = *(const float4*)(sp + i0);
    float4 z = *(const float4*)(zp + i0);
    float4 xv[8];
#pragma unroll
    for (int b = 0; b < 8; ++b)
        xv[b] = *(const float4*)(xp + b * IN_ + i0);

#pragma unroll
    for (int it = 0; it < ITERS; ++it) {
        // ---- issue ALL loads for iter+1 before computing iter ----
        int4 qa_n, qb_n;
        float4 s_n, z_n, xv_n[8];
        if (it + 1 < ITERS) {
            const int i = i0 + (it + 1) * 256;
            qa_n = *(const int4*)(wqA + i);
            qb_n = *(const int4*)(wqB + i);
            s_n  = *(const float4*)(sp + i);
            z_n  = *(const float4*)(zp + i);
#pragma unroll
            for (int b = 0; b < 8; ++b)
                xv_n[b] = *(const float4*)(xp + b * IN_ + i);
        }

        // ---- compute iter from current registers ----
        const float ss[4] = {s.x, s.y, s.z, s.w};
        const float zs[4] = {-z.x * s.x, -z.y * s.y, -z.z * s.z, -z.w * s.w};
        const int qsA[4] = {qa.x, qa.y, qa.z, qa.w};
        const int qsB[4] = {qb.x, qb.y, qb.z, qb.w};

        float w[4][4];  // [hiA, loA, hiB, loB][j]
#pragma unroll
        for (int j = 0; j < 4; ++j) {
            w[0][j] = fmaf((float)((qsA[j] >> 4) & 0xF), ss[j], zs[j]);
            w[1][j] = fmaf((float)( qsA[j]       & 0xF), ss[j], zs[j]);
            w[2][j] = fmaf((float)((qsB[j] >> 4) & 0xF), ss[j], zs[j]);
            w[3][j] = fmaf((float)( qsB[j]       & 0xF), ss[j], zs[j]);
        }
#pragma unroll
        for (int b = 0; b < 8; ++b) {
            const float4 xb = xv[b];
#pragma unroll
            for (int r = 0; r < 4; ++r) {
                float a = acc[r][b];
                a = fmaf(xb.x, w[r][0], a);
                a = fmaf(xb.y, w[r][1], a);
                a = fmaf(xb.z, w[r][2], a);
                a = fmaf(xb.w, w[r][3], a);
                acc[r][b] = a;
            }
        }

        // ---- rotate the double buffer ----
        if (it + 1 < ITERS) {
            qa = qa_n; qb = qb_n; s = s_n; z = z_n;
#pragma unroll
            for (int b = 0; b < 8; ++b) xv[b] = xv_n[b];
        }
    }

    // ---- reduce across the 64 K-slice lanes ----
#pragma unroll
    for (int r = 0; r < 4; ++r)
#pragma unroll
        for (int b = 0; b < 8; ++b) {
            float v = acc[r][b];
#pragma unroll
            for (int off = 32; off > 0; off >>= 1)
                v += __shfl_down(v, off, 64);
            acc[r][b] = v;
        }

    if (lane == 0) {
        const int o[4] = {rq0 * OC_ + oc, (rq0 + 32) * OC_ + oc,
                          (rq0 + 1) * OC_ + oc, (rq0 + 33) * OC_ + oc};
        float* __restrict__ wp = ws + (long)ks * 8 * OUT_;
#pragma unroll
        for (int r = 0; r < 4; ++r)
#pragma unroll
            for (int b = 0; b < 8; ++b)
                wp[b * OUT_ + o[r]] = acc[r][b];
    }
}

__global__ void hqq_reduce(const float* __restrict__ ws,
                           const float* __restrict__ bias,
                           float* __restrict__ out) {
    const int t = blockIdx.x * 256 + threadIdx.x;
    if (t >= 8 * OUT_) return;
    const int o = t % OUT_;
    float v = bias[o];
#pragma unroll
    for (int k = 0; k < KS; ++k) v += ws[k * 8 * OUT_ + t];
    out[t] = v;
}

extern "C" void kernel_launch(void* const* d_in, const int* in_sizes, int n_in,
                              void* d_out, int out_size, void* d_ws, size_t ws_size,
                              hipStream_t stream) {
    const int*   Wq    = (const int*)d_in[0];    // [32, 704512] int32
    const float* scale = (const float*)d_in[1];  // [1, 704512]
    const float* zero  = (const float*)d_in[2];  // [1, 704512]
    const float* x     = (const float*)d_in[3];  // [8, 1, 4096]
    const float* bias  = (const float*)d_in[4];  // [11008]
    float* out = (float*)d_out;                  // [8, 1, 11008]
    float* ws  = (float*)d_ws;                   // KS*8*11008 floats = 704 KB

    dim3 grid(16, OC_, KS);  // x: rq-pair, y: oc, z: K-split
    dim3 block(64);          // one wave per block — no barrier, no LDS
    hqq_gemv<<<grid, block, 0, stream>>>(Wq, scale, zero, x, ws);
    hqq_reduce<<<(8 * OUT_ + 255) / 256, 256, 0, stream>>>(ws, bias, out);
}

// Round 6
// 157.857 us; speedup vs baseline: 1.0122x; 1.0122x over previous
//
#include <hip/hip_runtime.h>

// HQQ 4-bit dequant + linear (Llama-7B up-proj, decode: 8 tokens)
// OUT=11008, IN=4096, GS=64, G=704512, OC=172 (=G/IN; OUT=64*OC)
// W_q: [32, G] int32 (one byte per word: hi nibble -> unpacked row rq,
//      lo nibble -> row rq+32 of the [64, G] tensor)
// Mapping: W_r[o, i] with r=o/172, oc=o%172, g=oc*4096+i.
// out[b, o] = sum_i x[b,i] * fma(nib, s[g], -z[g]*s[g]) + bias[o]
//
// R6 theory: gemv is pinned at ~48-73 us across ALL structures; surviving
// hypothesis is a per-CU global-read byte budget (~10 B/cyc/CU, m13). R4's
// total CU-side reads ~200 MB (x re-staging ~ Wq!). This version: 16 packed
// rows per block (4/wave, 64 accs) -> x staged by half the blocks; total
// reads ~145 MB. Wq register pipeline (depth-2) issued BEFORE staging +
// barrier so HBM flight overlaps the stage phase. 40 KB LDS, ~164 VGPR,
// 3 blocks/CU.

#define OUT_ 11008
#define IN_ 4096
#define G_ 704512
#define OC_ 172
#define KS 4              // K-split factor
#define KC (IN_ / KS)     // 1024 K per block
#define NIT (KC / 256)    // 4 iterations of 256 K

__global__ __launch_bounds__(256, 3)
void hqq_gemv(const int* __restrict__ Wq, const float* __restrict__ scale,
              const float* __restrict__ zero, const float* __restrict__ x,
              float* __restrict__ ws) {
    __shared__ float s_lds[KC];
    __shared__ float z_lds[KC];
    __shared__ float x_lds[8 * KC];

    const int lane = threadIdx.x;               // 0..63
    const int ty   = threadIdx.y;               // 0..3
    const int tid  = ty * 64 + lane;
    const int oc   = blockIdx.y;                // 0..171
    const int ks   = blockIdx.z;                // 0..KS-1
    const int rq0  = blockIdx.x * 16 + ty * 4;  // this wave: packed rows rq0..rq0+3

    const int kbase = ks * KC;
    const long gb = (long)oc * IN_ + kbase;
    const int i0 = lane * 4;

    const int* __restrict__ wq0 = Wq + (long)rq0 * G_ + gb;

    // ---- Wq register pipeline: issue iters 0,1 for all 4 rows FIRST ----
    int4 qc[4], qn[4];
#pragma unroll
    for (int r = 0; r < 4; ++r) qc[r] = *(const int4*)(wq0 + (long)r * G_ + i0);
#pragma unroll
    for (int r = 0; r < 4; ++r) qn[r] = *(const int4*)(wq0 + (long)r * G_ + i0 + 256);

    // ---- stage s/z (1 round) and x (8 rounds) into LDS ----
    {
        const int off = tid * 4;
        *(float4*)(s_lds + off) = *(const float4*)(scale + gb + off);
        *(float4*)(z_lds + off) = *(const float4*)(zero + gb + off);
    }
#pragma unroll
    for (int r = 0; r < 8; ++r) {
        const int off = r * 1024 + tid * 4;     // linear over [b][k]
        const int b = off >> 10;
        const int k = off & (KC - 1);
        *(float4*)(x_lds + off) = *(const float4*)(x + b * IN_ + kbase + k);
    }

    __syncthreads();

    // acc[rr*2+0][b] = hi row of rq0+rr, acc[rr*2+1][b] = lo row
    float acc[8][8];
#pragma unroll
    for (int r = 0; r < 8; ++r)
#pragma unroll
        for (int b = 0; b < 8; ++b) acc[r][b] = 0.f;

#pragma unroll
    for (int it = 0; it < NIT; ++it) {
        const int i = it * 256 + i0;

        // rotate pipeline: current <- qc, issue it+2
        int4 q[4];
#pragma unroll
        for (int r = 0; r < 4; ++r) q[r] = qc[r];
#pragma unroll
        for (int r = 0; r < 4; ++r) qc[r] = qn[r];
        if (it + 2 < NIT) {
#pragma unroll
            for (int r = 0; r < 4; ++r)
                qn[r] = *(const int4*)(wq0 + (long)r * G_ + i + 512);
        }

        const float4 s4 = *(const float4*)(s_lds + i);
        const float4 z4 = *(const float4*)(z_lds + i);
        const float ss[4] = {s4.x, s4.y, s4.z, s4.w};
        const float zs[4] = {-z4.x * s4.x, -z4.y * s4.y, -z4.z * s4.z, -z4.w * s4.w};

        float w[8][4];  // [rr*2 + hi/lo][j]
#pragma unroll
        for (int rr = 0; rr < 4; ++rr) {
            const int qs[4] = {q[rr].x, q[rr].y, q[rr].z, q[rr].w};
#pragma unroll
            for (int j = 0; j < 4; ++j) {
                w[rr * 2 + 0][j] = fmaf((float)((qs[j] >> 4) & 0xF), ss[j], zs[j]);
                w[rr * 2 + 1][j] = fmaf((float)( qs[j]       & 0xF), ss[j], zs[j]);
            }
        }
#pragma unroll
        for (int b = 0; b < 8; ++b) {
            const float4 xb = *(const float4*)(x_lds + b * KC + i);
#pragma unroll
            for (int r = 0; r < 8; ++r) {
                float a = acc[r][b];
                a = fmaf(xb.x, w[r][0], a);
                a = fmaf(xb.y, w[r][1], a);
                a = fmaf(xb.z, w[r][2], a);
                a = fmaf(xb.w, w[r][3], a);
                acc[r][b] = a;
            }
        }
    }

    // ---- reduce across the 64 K-slice lanes ----
#pragma unroll
    for (int r = 0; r < 8; ++r)
#pragma unroll
        for (int b = 0; b < 8; ++b) {
            float v = acc[r][b];
#pragma unroll
            for (int off = 32; off > 0; off >>= 1)
                v += __shfl_down(v, off, 64);
            acc[r][b] = v;
        }

    if (lane == 0) {
        float* __restrict__ wp = ws + (long)ks * 8 * OUT_;
#pragma unroll
        for (int rr = 0; rr < 4; ++rr) {
            const int o_hi = (rq0 + rr) * OC_ + oc;
            const int o_lo = (rq0 + rr + 32) * OC_ + oc;
#pragma unroll
            for (int b = 0; b < 8; ++b) {
                wp[b * OUT_ + o_hi] = acc[rr * 2 + 0][b];
                wp[b * OUT_ + o_lo] = acc[rr * 2 + 1][b];
            }
        }
    }
}

__global__ void hqq_reduce(const float* __restrict__ ws,
                           const float* __restrict__ bias,
                           float* __restrict__ out) {
    const int t = blockIdx.x * 256 + threadIdx.x;
    if (t >= 8 * OUT_) return;
    const int o = t % OUT_;
    float v = bias[o];
#pragma unroll
    for (int k = 0; k < KS; ++k) v += ws[k * 8 * OUT_ + t];
    out[t] = v;
}

extern "C" void kernel_launch(void* const* d_in, const int* in_sizes, int n_in,
                              void* d_out, int out_size, void* d_ws, size_t ws_size,
                              hipStream_t stream) {
    const int*   Wq    = (const int*)d_in[0];    // [32, 704512] int32
    const float* scale = (const float*)d_in[1];  // [1, 704512]
    const float* zero  = (const float*)d_in[2];  // [1, 704512]
    const float* x     = (const float*)d_in[3];  // [8, 1, 4096]
    const float* bias  = (const float*)d_in[4];  // [11008]
    float* out = (float*)d_out;                  // [8, 1, 11008]
    float* ws  = (float*)d_ws;                   // KS*8*11008 floats = 1.41 MB

    dim3 grid(2, OC_, KS);  // x: 16-packed-row group, y: oc, z: K-split
    dim3 block(64, 4);      // 4 waves, each owns 4 packed rows (8 out rows)
    hqq_gemv<<<grid, block, 0, stream>>>(Wq, scale, zero, x, ws);
    hqq_reduce<<<(8 * OUT_ + 255) / 256, 256, 0, stream>>>(ws, bias, out);
}